// Round 3
// baseline (980.232 us; speedup 1.0000x reference)
//
#include <hip/hip_runtime.h>
#include <hip/hip_bf16.h>

constexpr int NN = 100000;   // nodes
constexpr int NE = 3200000;  // edges
constexpr int BSHIFT = 7;                       // 128 dsts per bucket
constexpr int BSPAN  = 1 << BSHIFT;
constexpr int NB = (NN + BSPAN - 1) >> BSHIFT;  // 782 buckets
constexpr int CAP = 5632;                       // mean 4096 + 24 sigma
constexpr int NBLK = 512;                       // bucket-pass blocks
constexpr int CHUNK = (NE + NBLK - 1) / NBLK;   // 6250 edges per block

// ---------------------------------------------------------------------------
// Coarse bucket sort: edges grouped by dst>>7. Per-block LDS histogram ->
// one global atomicAdd per (block,bucket) -> per-bucket contiguous segments.
// Payload: int2 { (dst&127)<<17 | src , bits(w) }.
// ---------------------------------------------------------------------------
__global__ __launch_bounds__(256) void k_bucket(
    const int* __restrict__ ei, const float* __restrict__ ew,
    int* __restrict__ gcursor, int2* __restrict__ e_sw)
{
    __shared__ int h[NB];
    __shared__ int base[NB];
    __shared__ int off[NB];
    int tid = threadIdx.x;
    int e0 = blockIdx.x * CHUNK;
    int e1 = e0 + CHUNK; if (e1 > NE) e1 = NE;
    for (int b = tid; b < NB; b += 256) { h[b] = 0; off[b] = 0; }
    __syncthreads();
    for (int e = e0 + tid; e < e1; e += 256)
        atomicAdd(&h[ei[NE + e] >> BSHIFT], 1);
    __syncthreads();
    for (int b = tid; b < NB; b += 256)
        base[b] = atomicAdd(&gcursor[b], h[b]);
    __syncthreads();
    for (int e = e0 + tid; e < e1; e += 256) {
        int d = ei[NE + e];
        int b = d >> BSHIFT;
        int p = base[b] + atomicAdd(&off[b], 1);
        int2 v;
        v.x = ((d & (BSPAN - 1)) << 17) | ei[e];
        v.y = __float_as_int(ew[e]);
        e_sw[(size_t)b * CAP + p] = v;
    }
}

// ---------------------------------------------------------------------------
// y1 = x @ W1_rel.T   (N x 64 -> N x 32); one thread per node.
// ---------------------------------------------------------------------------
__global__ __launch_bounds__(256) void k_transform1(
    const float* __restrict__ x, const float* __restrict__ W1_rel,
    float* __restrict__ y1)
{
    int n = blockIdx.x * 256 + threadIdx.x;
    if (n >= NN) return;
    float xr[64];
    const float4* xrow = reinterpret_cast<const float4*>(x + (size_t)n * 64);
#pragma unroll
    for (int i = 0; i < 16; ++i) {
        float4 v = xrow[i];
        xr[4*i+0] = v.x; xr[4*i+1] = v.y; xr[4*i+2] = v.z; xr[4*i+3] = v.w;
    }
    float4* out = reinterpret_cast<float4*>(y1 + (size_t)n * 32);
#pragma unroll
    for (int og = 0; og < 8; ++og) {
        float a[4];
#pragma unroll
        for (int j = 0; j < 4; ++j) {
            const float* wrow = W1_rel + (og * 4 + j) * 64;
            float s = 0.f;
#pragma unroll
            for (int k = 0; k < 64; ++k) s += xr[k] * wrow[k];
            a[j] = s;
        }
        float4 v; v.x = a[0]; v.y = a[1]; v.z = a[2]; v.w = a[3];
        out[og] = v;
    }
}

// ---------------------------------------------------------------------------
// Reduce pass 1: one block per bucket; 8 lanes per edge (float4 of the 32
// features each); accumulate into LDS tile via ds_add_f32; coalesced writeout.
// ---------------------------------------------------------------------------
__global__ __launch_bounds__(256) void k_reduce1(
    const int* __restrict__ gcursor, const int2* __restrict__ e_sw,
    const float* __restrict__ y1, float* __restrict__ agg1)
{
    __shared__ float agg[BSPAN * 33];
    int tid = threadIdx.x;
    int b = blockIdx.x;
    for (int i = tid; i < BSPAN * 33; i += 256) agg[i] = 0.f;
    __syncthreads();
    int cnt = gcursor[b];
    const int2* es = e_sw + (size_t)b * CAP;
    int g = tid & 7;
    for (int i = tid >> 3; i < cnt; i += 32) {
        int2 sw = es[i];
        float w = __int_as_float(sw.y);
        int src = sw.x & 0x1FFFF;
        int dl  = sw.x >> 17;
        float4 v = *reinterpret_cast<const float4*>(y1 + (size_t)src * 32 + g * 4);
        float* a = &agg[dl * 33 + g * 4];
        atomicAdd(a + 0, v.x * w);
        atomicAdd(a + 1, v.y * w);
        atomicAdd(a + 2, v.z * w);
        atomicAdd(a + 3, v.w * w);
    }
    __syncthreads();
    int dstBase = b << BSHIFT;
    int nd = NN - dstBase; if (nd > BSPAN) nd = BSPAN;
    for (int k = tid; k < nd * 32; k += 256) {
        int d = k >> 5, f = k & 31;
        agg1[(size_t)(dstBase + d) * 32 + f] = agg[d * 33 + f];
    }
}

// ---------------------------------------------------------------------------
// h = relu(agg1 + b1 + x @ W1_root.T); y2 = h @ W2_rel.T; r2 = h @ W2_root.T
// ---------------------------------------------------------------------------
__global__ __launch_bounds__(256) void k_node1(
    const float* __restrict__ x, const float* __restrict__ agg1,
    const float* __restrict__ W1_root, const float* __restrict__ b1,
    const float* __restrict__ W2_rel, const float* __restrict__ W2_root,
    float* __restrict__ y2, float* __restrict__ r2)
{
    int n = blockIdx.x * 256 + threadIdx.x;
    if (n >= NN) return;
    float xr[64];
    const float4* xrow = reinterpret_cast<const float4*>(x + (size_t)n * 64);
#pragma unroll
    for (int i = 0; i < 16; ++i) {
        float4 v = xrow[i];
        xr[4*i+0] = v.x; xr[4*i+1] = v.y; xr[4*i+2] = v.z; xr[4*i+3] = v.w;
    }
    float h[32];
    const float4* arow = reinterpret_cast<const float4*>(agg1 + (size_t)n * 32);
#pragma unroll
    for (int og = 0; og < 8; ++og) {
        float4 v = arow[og];
        h[og*4+0] = v.x; h[og*4+1] = v.y; h[og*4+2] = v.z; h[og*4+3] = v.w;
    }
#pragma unroll
    for (int o = 0; o < 32; ++o) {
        const float* wrow = W1_root + o * 64;
        float s = 0.f;
#pragma unroll
        for (int k = 0; k < 64; ++k) s += xr[k] * wrow[k];
        float t = h[o] + b1[o] + s;
        h[o] = t > 0.f ? t : 0.f;
    }
    float o2[8], o3[8];
#pragma unroll
    for (int j = 0; j < 8; ++j) {
        const float* wr = W2_rel  + j * 32;
        const float* wo = W2_root + j * 32;
        float s0 = 0.f, s1 = 0.f;
#pragma unroll
        for (int c = 0; c < 32; ++c) { s0 += h[c] * wr[c]; s1 += h[c] * wo[c]; }
        o2[j] = s0; o3[j] = s1;
    }
    float4* y2o = reinterpret_cast<float4*>(y2 + (size_t)n * 8);
    float4* r2o = reinterpret_cast<float4*>(r2 + (size_t)n * 8);
    float4 v0, v1;
    v0.x=o2[0]; v0.y=o2[1]; v0.z=o2[2]; v0.w=o2[3]; y2o[0]=v0;
    v1.x=o2[4]; v1.y=o2[5]; v1.z=o2[6]; v1.w=o2[7]; y2o[1]=v1;
    v0.x=o3[0]; v0.y=o3[1]; v0.z=o3[2]; v0.w=o3[3]; r2o[0]=v0;
    v1.x=o3[4]; v1.y=o3[5]; v1.z=o3[6]; v1.w=o3[7]; r2o[1]=v1;
}

// ---------------------------------------------------------------------------
// Reduce pass 2: one block per bucket; 1 thread per edge (8 features).
// ---------------------------------------------------------------------------
__global__ __launch_bounds__(256) void k_reduce2(
    const int* __restrict__ gcursor, const int2* __restrict__ e_sw,
    const float* __restrict__ y2, float* __restrict__ agg2)
{
    __shared__ float agg[BSPAN * 9];
    int tid = threadIdx.x;
    int b = blockIdx.x;
    for (int i = tid; i < BSPAN * 9; i += 256) agg[i] = 0.f;
    __syncthreads();
    int cnt = gcursor[b];
    const int2* es = e_sw + (size_t)b * CAP;
    for (int i = tid; i < cnt; i += 256) {
        int2 sw = es[i];
        float w = __int_as_float(sw.y);
        int src = sw.x & 0x1FFFF;
        int dl  = sw.x >> 17;
        const float4* yr = reinterpret_cast<const float4*>(y2 + (size_t)src * 8);
        float4 v0 = yr[0], v1 = yr[1];
        float* a = &agg[dl * 9];
        atomicAdd(a + 0, v0.x * w);
        atomicAdd(a + 1, v0.y * w);
        atomicAdd(a + 2, v0.z * w);
        atomicAdd(a + 3, v0.w * w);
        atomicAdd(a + 4, v1.x * w);
        atomicAdd(a + 5, v1.y * w);
        atomicAdd(a + 6, v1.z * w);
        atomicAdd(a + 7, v1.w * w);
    }
    __syncthreads();
    int dstBase = b << BSHIFT;
    int nd = NN - dstBase; if (nd > BSPAN) nd = BSPAN;
    for (int k = tid; k < nd * 8; k += 256) {
        int d = k >> 3, f = k & 7;
        agg2[(size_t)(dstBase + d) * 8 + f] = agg[d * 9 + f];
    }
}

// ---------------------------------------------------------------------------
// Final: h2 = agg2 + b2 + r2; emb = log_softmax(h2); out = relu([emb,x1]@W_lin.T+b)
// ---------------------------------------------------------------------------
__global__ __launch_bounds__(256) void k_final(
    const float* __restrict__ agg2, const float* __restrict__ r2,
    const float* __restrict__ x1, const float* __restrict__ b2,
    const float* __restrict__ W_lin, const float* __restrict__ b_lin,
    float* __restrict__ outv, float* __restrict__ emb)
{
    int n = blockIdx.x * 256 + threadIdx.x;
    if (n >= NN) return;
    const float4* arow = reinterpret_cast<const float4*>(agg2 + (size_t)n * 8);
    const float4* rrow = reinterpret_cast<const float4*>(r2   + (size_t)n * 8);
    float h2[8];
    {
        float4 a0 = arow[0], a1 = arow[1], r0 = rrow[0], r1 = rrow[1];
        h2[0]=a0.x+r0.x+b2[0]; h2[1]=a0.y+r0.y+b2[1];
        h2[2]=a0.z+r0.z+b2[2]; h2[3]=a0.w+r0.w+b2[3];
        h2[4]=a1.x+r1.x+b2[4]; h2[5]=a1.y+r1.y+b2[5];
        h2[6]=a1.z+r1.z+b2[6]; h2[7]=a1.w+r1.w+b2[7];
    }
    float m = h2[0];
#pragma unroll
    for (int j = 1; j < 8; ++j) m = fmaxf(m, h2[j]);
    float sum = 0.f;
#pragma unroll
    for (int j = 0; j < 8; ++j) sum += __expf(h2[j] - m);
    float lse = __logf(sum);
    float eb[8];
#pragma unroll
    for (int j = 0; j < 8; ++j) eb[j] = h2[j] - m - lse;
    float4* eo = reinterpret_cast<float4*>(emb + (size_t)n * 8);
    float4 v0, v1;
    v0.x=eb[0]; v0.y=eb[1]; v0.z=eb[2]; v0.w=eb[3]; eo[0]=v0;
    v1.x=eb[4]; v1.y=eb[5]; v1.z=eb[6]; v1.w=eb[7]; eo[1]=v1;
    float acc = b_lin[0] + x1[n] * W_lin[8];
#pragma unroll
    for (int j = 0; j < 8; ++j) acc += eb[j] * W_lin[j];
    outv[n] = acc > 0.f ? acc : 0.f;
}

// ---------------------------------------------------------------------------
extern "C" void kernel_launch(void* const* d_in, const int* in_sizes, int n_in,
                              void* d_out, int out_size, void* d_ws, size_t ws_size,
                              hipStream_t stream) {
    const float* x      = (const float*)d_in[0];
    const int*   ei     = (const int*)  d_in[1];
    const float* ew     = (const float*)d_in[2];
    const float* x1     = (const float*)d_in[3];
    const float* W1_rel = (const float*)d_in[4];
    const float* b1     = (const float*)d_in[5];
    const float* W1_root= (const float*)d_in[6];
    const float* W2_rel = (const float*)d_in[7];
    const float* b2     = (const float*)d_in[8];
    const float* W2_root= (const float*)d_in[9];
    const float* W_lin  = (const float*)d_in[10];
    const float* b_lin  = (const float*)d_in[11];

    float* ws   = (float*)d_ws;
    float* y1   = ws;                        // N*32
    float* agg1 = y1   + (size_t)NN * 32;    // N*32
    float* y2   = agg1 + (size_t)NN * 32;    // N*8
    float* r2   = y2   + (size_t)NN * 8;     // N*8
    float* agg2 = r2   + (size_t)NN * 8;     // N*8
    int*   gcursor = (int*)(agg2 + (size_t)NN * 8); // NB (even count keeps 8B align)
    int2*  e_sw = (int2*)(gcursor + NB + (NB & 1)); // NB*CAP int2

    float* outv = (float*)d_out;             // N   (output 0)
    float* emb  = outv + NN;                 // N*8 (output 1)

    hipMemsetAsync(gcursor, 0, NB * sizeof(int), stream);

    int nbN = (NN + 255) / 256;
    k_bucket<<<NBLK, 256, 0, stream>>>(ei, ew, gcursor, e_sw);
    k_transform1<<<nbN, 256, 0, stream>>>(x, W1_rel, y1);
    k_reduce1<<<NB, 256, 0, stream>>>(gcursor, e_sw, y1, agg1);
    k_node1<<<nbN, 256, 0, stream>>>(x, agg1, W1_root, b1, W2_rel, W2_root, y2, r2);
    k_reduce2<<<NB, 256, 0, stream>>>(gcursor, e_sw, y2, agg2);
    k_final<<<nbN, 256, 0, stream>>>(agg2, r2, x1, b2, W_lin, b_lin, outv, emb);
}

// Round 4
// 873.580 us; speedup vs baseline: 1.1221x; 1.1221x over previous
//
#include <hip/hip_runtime.h>
#include <hip/hip_bf16.h>

constexpr int NN = 100000;   // nodes
constexpr int NE = 3200000;  // edges
constexpr int BSHIFT = 7;                       // 128 dsts per bucket
constexpr int BSPAN  = 1 << BSHIFT;
constexpr int NB = (NN + BSPAN - 1) >> BSHIFT;  // 782 buckets
constexpr int CAP = 5632;                       // mean 4096 + 24 sigma
constexpr int NBLK = 512;                       // bucket-pass blocks
constexpr int CHUNK = (NE + NBLK - 1) / NBLK;   // 6250 edges per block
constexpr int S1 = 2;                           // reduce1 sub-blocks per bucket
constexpr int S2 = 4;                           // reduce2 sub-blocks per bucket

// ---------------------------------------------------------------------------
// Coarse bucket sort: edges grouped by dst>>7. Per-block LDS histogram ->
// one global atomicAdd per (block,bucket) -> per-bucket contiguous segments.
// Payload: int2 { (dst&127)<<17 | src , bits(w) }.
// ---------------------------------------------------------------------------
__global__ __launch_bounds__(256) void k_bucket(
    const int* __restrict__ ei, const float* __restrict__ ew,
    int* __restrict__ gcursor, int2* __restrict__ e_sw)
{
    __shared__ int h[NB];
    __shared__ int base[NB];
    __shared__ int off[NB];
    int tid = threadIdx.x;
    int e0 = blockIdx.x * CHUNK;
    int e1 = e0 + CHUNK; if (e1 > NE) e1 = NE;
    for (int b = tid; b < NB; b += 256) { h[b] = 0; off[b] = 0; }
    __syncthreads();
    for (int e = e0 + tid; e < e1; e += 256)
        atomicAdd(&h[ei[NE + e] >> BSHIFT], 1);
    __syncthreads();
    for (int b = tid; b < NB; b += 256)
        base[b] = atomicAdd(&gcursor[b], h[b]);
    __syncthreads();
    for (int e = e0 + tid; e < e1; e += 256) {
        int d = ei[NE + e];
        int b = d >> BSHIFT;
        int p = base[b] + atomicAdd(&off[b], 1);
        int2 v;
        v.x = ((d & (BSPAN - 1)) << 17) | ei[e];
        v.y = __float_as_int(ew[e]);
        e_sw[(size_t)b * CAP + p] = v;
    }
}

// ---------------------------------------------------------------------------
// y1 = x @ W1_rel.T   (N x 64 -> N x 32); one thread per node.
// ---------------------------------------------------------------------------
__global__ __launch_bounds__(256) void k_transform1(
    const float* __restrict__ x, const float* __restrict__ W1_rel,
    float* __restrict__ y1)
{
    int n = blockIdx.x * 256 + threadIdx.x;
    if (n >= NN) return;
    float xr[64];
    const float4* xrow = reinterpret_cast<const float4*>(x + (size_t)n * 64);
#pragma unroll
    for (int i = 0; i < 16; ++i) {
        float4 v = xrow[i];
        xr[4*i+0] = v.x; xr[4*i+1] = v.y; xr[4*i+2] = v.z; xr[4*i+3] = v.w;
    }
    float4* out = reinterpret_cast<float4*>(y1 + (size_t)n * 32);
#pragma unroll
    for (int og = 0; og < 8; ++og) {
        float a[4];
#pragma unroll
        for (int j = 0; j < 4; ++j) {
            const float* wrow = W1_rel + (og * 4 + j) * 64;
            float s = 0.f;
#pragma unroll
            for (int k = 0; k < 64; ++k) s += xr[k] * wrow[k];
            a[j] = s;
        }
        float4 v; v.x = a[0]; v.y = a[1]; v.z = a[2]; v.w = a[3];
        out[og] = v;
    }
}

// ---------------------------------------------------------------------------
// Reduce pass 1: S1 blocks per bucket, each covers a sub-range of the
// bucket's edges. 8 lanes per edge. 4x manual unroll for MLP. LDS tile,
// one coalesced partial-plane write, no global atomics.
// ---------------------------------------------------------------------------
__global__ __launch_bounds__(256) void k_reduce1(
    const int* __restrict__ gcursor, const int2* __restrict__ e_sw,
    const float* __restrict__ y1, float* __restrict__ part1)
{
    __shared__ float agg[BSPAN * 33];
    int tid = threadIdx.x;
    int b = blockIdx.x / S1;
    int s = blockIdx.x % S1;
    for (int i = tid; i < BSPAN * 33; i += 256) agg[i] = 0.f;
    __syncthreads();
    int cnt = gcursor[b];
    int i0 = (cnt * s) / S1;
    int i1 = (cnt * (s + 1)) / S1;
    const int2* es = e_sw + (size_t)b * CAP;
    int g  = tid & 7;
    int lg = tid >> 3;          // lane-group 0..31
    int i = i0 + lg;
    for (; i + 96 < i1; i += 128) {
        int2 eA = es[i];
        int2 eB = es[i + 32];
        int2 eC = es[i + 64];
        int2 eD = es[i + 96];
        float4 vA = *reinterpret_cast<const float4*>(y1 + (size_t)(eA.x & 0x1FFFF) * 32 + g * 4);
        float4 vB = *reinterpret_cast<const float4*>(y1 + (size_t)(eB.x & 0x1FFFF) * 32 + g * 4);
        float4 vC = *reinterpret_cast<const float4*>(y1 + (size_t)(eC.x & 0x1FFFF) * 32 + g * 4);
        float4 vD = *reinterpret_cast<const float4*>(y1 + (size_t)(eD.x & 0x1FFFF) * 32 + g * 4);
        float wA = __int_as_float(eA.y), wB = __int_as_float(eB.y);
        float wC = __int_as_float(eC.y), wD = __int_as_float(eD.y);
        float* aA = &agg[(eA.x >> 17) * 33 + g * 4];
        float* aB = &agg[(eB.x >> 17) * 33 + g * 4];
        float* aC = &agg[(eC.x >> 17) * 33 + g * 4];
        float* aD = &agg[(eD.x >> 17) * 33 + g * 4];
        atomicAdd(aA + 0, vA.x * wA); atomicAdd(aA + 1, vA.y * wA);
        atomicAdd(aA + 2, vA.z * wA); atomicAdd(aA + 3, vA.w * wA);
        atomicAdd(aB + 0, vB.x * wB); atomicAdd(aB + 1, vB.y * wB);
        atomicAdd(aB + 2, vB.z * wB); atomicAdd(aB + 3, vB.w * wB);
        atomicAdd(aC + 0, vC.x * wC); atomicAdd(aC + 1, vC.y * wC);
        atomicAdd(aC + 2, vC.z * wC); atomicAdd(aC + 3, vC.w * wC);
        atomicAdd(aD + 0, vD.x * wD); atomicAdd(aD + 1, vD.y * wD);
        atomicAdd(aD + 2, vD.z * wD); atomicAdd(aD + 3, vD.w * wD);
    }
    for (; i < i1; i += 32) {
        int2 sw = es[i];
        float w = __int_as_float(sw.y);
        float4 v = *reinterpret_cast<const float4*>(y1 + (size_t)(sw.x & 0x1FFFF) * 32 + g * 4);
        float* a = &agg[(sw.x >> 17) * 33 + g * 4];
        atomicAdd(a + 0, v.x * w); atomicAdd(a + 1, v.y * w);
        atomicAdd(a + 2, v.z * w); atomicAdd(a + 3, v.w * w);
    }
    __syncthreads();
    int dstBase = b << BSHIFT;
    int nd = NN - dstBase; if (nd > BSPAN) nd = BSPAN;
    float* plane = part1 + (size_t)s * NN * 32;
    for (int k = tid; k < nd * 32; k += 256) {
        int d = k >> 5, f = k & 31;
        plane[(size_t)(dstBase + d) * 32 + f] = agg[d * 33 + f];
    }
}

// ---------------------------------------------------------------------------
// h = relu(sum_s part1 + b1 + x @ W1_root.T); y2 = h @ W2_rel.T; r2 = h @ W2_root.T
// ---------------------------------------------------------------------------
__global__ __launch_bounds__(256) void k_node1(
    const float* __restrict__ x, const float* __restrict__ part1,
    const float* __restrict__ W1_root, const float* __restrict__ b1,
    const float* __restrict__ W2_rel, const float* __restrict__ W2_root,
    float* __restrict__ y2, float* __restrict__ r2)
{
    int n = blockIdx.x * 256 + threadIdx.x;
    if (n >= NN) return;
    float xr[64];
    const float4* xrow = reinterpret_cast<const float4*>(x + (size_t)n * 64);
#pragma unroll
    for (int i = 0; i < 16; ++i) {
        float4 v = xrow[i];
        xr[4*i+0] = v.x; xr[4*i+1] = v.y; xr[4*i+2] = v.z; xr[4*i+3] = v.w;
    }
    float h[32];
    const float4* p0 = reinterpret_cast<const float4*>(part1 + (size_t)n * 32);
    const float4* p1 = reinterpret_cast<const float4*>(part1 + (size_t)NN * 32 + (size_t)n * 32);
#pragma unroll
    for (int og = 0; og < 8; ++og) {
        float4 a = p0[og], bq = p1[og];
        h[og*4+0] = a.x + bq.x; h[og*4+1] = a.y + bq.y;
        h[og*4+2] = a.z + bq.z; h[og*4+3] = a.w + bq.w;
    }
#pragma unroll
    for (int o = 0; o < 32; ++o) {
        const float* wrow = W1_root + o * 64;
        float ssum = 0.f;
#pragma unroll
        for (int k = 0; k < 64; ++k) ssum += xr[k] * wrow[k];
        float t = h[o] + b1[o] + ssum;
        h[o] = t > 0.f ? t : 0.f;
    }
    float o2[8], o3[8];
#pragma unroll
    for (int j = 0; j < 8; ++j) {
        const float* wr = W2_rel  + j * 32;
        const float* wo = W2_root + j * 32;
        float s0 = 0.f, s1 = 0.f;
#pragma unroll
        for (int c = 0; c < 32; ++c) { s0 += h[c] * wr[c]; s1 += h[c] * wo[c]; }
        o2[j] = s0; o3[j] = s1;
    }
    float4* y2o = reinterpret_cast<float4*>(y2 + (size_t)n * 8);
    float4* r2o = reinterpret_cast<float4*>(r2 + (size_t)n * 8);
    float4 v0, v1;
    v0.x=o2[0]; v0.y=o2[1]; v0.z=o2[2]; v0.w=o2[3]; y2o[0]=v0;
    v1.x=o2[4]; v1.y=o2[5]; v1.z=o2[6]; v1.w=o2[7]; y2o[1]=v1;
    v0.x=o3[0]; v0.y=o3[1]; v0.z=o3[2]; v0.w=o3[3]; r2o[0]=v0;
    v1.x=o3[4]; v1.y=o3[5]; v1.z=o3[6]; v1.w=o3[7]; r2o[1]=v1;
}

// ---------------------------------------------------------------------------
// Reduce pass 2: S2 blocks per bucket; 1 thread per edge (8 features);
// 4x unroll. LDS tile + partial planes.
// ---------------------------------------------------------------------------
__global__ __launch_bounds__(256) void k_reduce2(
    const int* __restrict__ gcursor, const int2* __restrict__ e_sw,
    const float* __restrict__ y2, float* __restrict__ part2)
{
    __shared__ float agg[BSPAN * 9];
    int tid = threadIdx.x;
    int b = blockIdx.x / S2;
    int s = blockIdx.x % S2;
    for (int i = tid; i < BSPAN * 9; i += 256) agg[i] = 0.f;
    __syncthreads();
    int cnt = gcursor[b];
    int i0 = (cnt * s) / S2;
    int i1 = (cnt * (s + 1)) / S2;
    const int2* es = e_sw + (size_t)b * CAP;
    int i = i0 + tid;
    for (; i + 768 < i1; i += 1024) {
        int2 eA = es[i];
        int2 eB = es[i + 256];
        int2 eC = es[i + 512];
        int2 eD = es[i + 768];
        const float4* rA = reinterpret_cast<const float4*>(y2 + (size_t)(eA.x & 0x1FFFF) * 8);
        const float4* rB = reinterpret_cast<const float4*>(y2 + (size_t)(eB.x & 0x1FFFF) * 8);
        const float4* rC = reinterpret_cast<const float4*>(y2 + (size_t)(eC.x & 0x1FFFF) * 8);
        const float4* rD = reinterpret_cast<const float4*>(y2 + (size_t)(eD.x & 0x1FFFF) * 8);
        float4 a0 = rA[0], a1 = rA[1], b0 = rB[0], b1v = rB[1];
        float4 c0 = rC[0], c1 = rC[1], d0 = rD[0], d1 = rD[1];
        float wA = __int_as_float(eA.y), wB = __int_as_float(eB.y);
        float wC = __int_as_float(eC.y), wD = __int_as_float(eD.y);
        float* pA = &agg[(eA.x >> 17) * 9];
        float* pB = &agg[(eB.x >> 17) * 9];
        float* pC = &agg[(eC.x >> 17) * 9];
        float* pD = &agg[(eD.x >> 17) * 9];
        atomicAdd(pA+0,a0.x*wA); atomicAdd(pA+1,a0.y*wA); atomicAdd(pA+2,a0.z*wA); atomicAdd(pA+3,a0.w*wA);
        atomicAdd(pA+4,a1.x*wA); atomicAdd(pA+5,a1.y*wA); atomicAdd(pA+6,a1.z*wA); atomicAdd(pA+7,a1.w*wA);
        atomicAdd(pB+0,b0.x*wB); atomicAdd(pB+1,b0.y*wB); atomicAdd(pB+2,b0.z*wB); atomicAdd(pB+3,b0.w*wB);
        atomicAdd(pB+4,b1v.x*wB); atomicAdd(pB+5,b1v.y*wB); atomicAdd(pB+6,b1v.z*wB); atomicAdd(pB+7,b1v.w*wB);
        atomicAdd(pC+0,c0.x*wC); atomicAdd(pC+1,c0.y*wC); atomicAdd(pC+2,c0.z*wC); atomicAdd(pC+3,c0.w*wC);
        atomicAdd(pC+4,c1.x*wC); atomicAdd(pC+5,c1.y*wC); atomicAdd(pC+6,c1.z*wC); atomicAdd(pC+7,c1.w*wC);
        atomicAdd(pD+0,d0.x*wD); atomicAdd(pD+1,d0.y*wD); atomicAdd(pD+2,d0.z*wD); atomicAdd(pD+3,d0.w*wD);
        atomicAdd(pD+4,d1.x*wD); atomicAdd(pD+5,d1.y*wD); atomicAdd(pD+6,d1.z*wD); atomicAdd(pD+7,d1.w*wD);
    }
    for (; i < i1; i += 256) {
        int2 sw = es[i];
        float w = __int_as_float(sw.y);
        const float4* yr = reinterpret_cast<const float4*>(y2 + (size_t)(sw.x & 0x1FFFF) * 8);
        float4 v0 = yr[0], v1 = yr[1];
        float* a = &agg[(sw.x >> 17) * 9];
        atomicAdd(a+0,v0.x*w); atomicAdd(a+1,v0.y*w); atomicAdd(a+2,v0.z*w); atomicAdd(a+3,v0.w*w);
        atomicAdd(a+4,v1.x*w); atomicAdd(a+5,v1.y*w); atomicAdd(a+6,v1.z*w); atomicAdd(a+7,v1.w*w);
    }
    __syncthreads();
    int dstBase = b << BSHIFT;
    int nd = NN - dstBase; if (nd > BSPAN) nd = BSPAN;
    float* plane = part2 + (size_t)s * NN * 8;
    for (int k = tid; k < nd * 8; k += 256) {
        int d = k >> 3, f = k & 7;
        plane[(size_t)(dstBase + d) * 8 + f] = agg[d * 9 + f];
    }
}

// ---------------------------------------------------------------------------
// Final: h2 = sum_s part2 + b2 + r2; emb = log_softmax(h2);
// out = relu([emb,x1]@W_lin.T+b)
// ---------------------------------------------------------------------------
__global__ __launch_bounds__(256) void k_final(
    const float* __restrict__ part2, const float* __restrict__ r2,
    const float* __restrict__ x1, const float* __restrict__ b2,
    const float* __restrict__ W_lin, const float* __restrict__ b_lin,
    float* __restrict__ outv, float* __restrict__ emb)
{
    int n = blockIdx.x * 256 + threadIdx.x;
    if (n >= NN) return;
    const float4* rrow = reinterpret_cast<const float4*>(r2 + (size_t)n * 8);
    float4 r0 = rrow[0], r1 = rrow[1];
    float h2[8] = { r0.x + b2[0], r0.y + b2[1], r0.z + b2[2], r0.w + b2[3],
                    r1.x + b2[4], r1.y + b2[5], r1.z + b2[6], r1.w + b2[7] };
#pragma unroll
    for (int s = 0; s < S2; ++s) {
        const float4* pp = reinterpret_cast<const float4*>(part2 + (size_t)s * NN * 8 + (size_t)n * 8);
        float4 a0 = pp[0], a1 = pp[1];
        h2[0]+=a0.x; h2[1]+=a0.y; h2[2]+=a0.z; h2[3]+=a0.w;
        h2[4]+=a1.x; h2[5]+=a1.y; h2[6]+=a1.z; h2[7]+=a1.w;
    }
    float m = h2[0];
#pragma unroll
    for (int j = 1; j < 8; ++j) m = fmaxf(m, h2[j]);
    float sum = 0.f;
#pragma unroll
    for (int j = 0; j < 8; ++j) sum += __expf(h2[j] - m);
    float lse = __logf(sum);
    float eb[8];
#pragma unroll
    for (int j = 0; j < 8; ++j) eb[j] = h2[j] - m - lse;
    float4* eo = reinterpret_cast<float4*>(emb + (size_t)n * 8);
    float4 v0, v1;
    v0.x=eb[0]; v0.y=eb[1]; v0.z=eb[2]; v0.w=eb[3]; eo[0]=v0;
    v1.x=eb[4]; v1.y=eb[5]; v1.z=eb[6]; v1.w=eb[7]; eo[1]=v1;
    float acc = b_lin[0] + x1[n] * W_lin[8];
#pragma unroll
    for (int j = 0; j < 8; ++j) acc += eb[j] * W_lin[j];
    outv[n] = acc > 0.f ? acc : 0.f;
}

// ---------------------------------------------------------------------------
extern "C" void kernel_launch(void* const* d_in, const int* in_sizes, int n_in,
                              void* d_out, int out_size, void* d_ws, size_t ws_size,
                              hipStream_t stream) {
    const float* x      = (const float*)d_in[0];
    const int*   ei     = (const int*)  d_in[1];
    const float* ew     = (const float*)d_in[2];
    const float* x1     = (const float*)d_in[3];
    const float* W1_rel = (const float*)d_in[4];
    const float* b1     = (const float*)d_in[5];
    const float* W1_root= (const float*)d_in[6];
    const float* W2_rel = (const float*)d_in[7];
    const float* b2     = (const float*)d_in[8];
    const float* W2_root= (const float*)d_in[9];
    const float* W_lin  = (const float*)d_in[10];
    const float* b_lin  = (const float*)d_in[11];

    float* ws   = (float*)d_ws;
    float* y1    = ws;                           // N*32
    float* part1 = y1 + (size_t)NN * 32;         // S1 * N*32
    float* y2    = part1 + (size_t)S1 * NN * 32; // N*8
    float* r2    = y2 + (size_t)NN * 8;          // N*8
    float* part2 = part1;                        // S2 * N*8 (aliases dead part1)
    int*   gcursor = (int*)(r2 + (size_t)NN * 8);       // NB
    int2*  e_sw = (int2*)(gcursor + NB + (NB & 1));     // NB*CAP int2

    float* outv = (float*)d_out;             // N   (output 0)
    float* emb  = outv + NN;                 // N*8 (output 1)

    hipMemsetAsync(gcursor, 0, NB * sizeof(int), stream);

    int nbN = (NN + 255) / 256;
    k_bucket<<<NBLK, 256, 0, stream>>>(ei, ew, gcursor, e_sw);
    k_transform1<<<nbN, 256, 0, stream>>>(x, W1_rel, y1);
    k_reduce1<<<NB * S1, 256, 0, stream>>>(gcursor, e_sw, y1, part1);
    k_node1<<<nbN, 256, 0, stream>>>(x, part1, W1_root, b1, W2_rel, W2_root, y2, r2);
    k_reduce2<<<NB * S2, 256, 0, stream>>>(gcursor, e_sw, y2, part2);
    k_final<<<nbN, 256, 0, stream>>>(part2, r2, x1, b2, W_lin, b_lin, outv, emb);
}

// Round 5
// 261.410 us; speedup vs baseline: 3.7498x; 3.3418x over previous
//
#include <hip/hip_runtime.h>
#include <hip/hip_bf16.h>

constexpr int NN = 100000;   // nodes
constexpr int NE = 3200000;  // edges
constexpr int BSHIFT = 7;                       // 128 dsts per bucket
constexpr int BSPAN  = 1 << BSHIFT;
constexpr int NB = (NN + BSPAN - 1) >> BSHIFT;  // 782 buckets
constexpr int CAP = 5632;                       // mean 4096 + 24 sigma
constexpr int NBLK = 512;                       // bucket-pass blocks
constexpr int CHUNK = (NE + NBLK - 1) / NBLK;   // 6250 edges per block

// ---------------------------------------------------------------------------
// Pass A: coarse bucket sort by dst>>7 (unchanged from round 4).
// Payload: int2 { (dst&127)<<17 | src , bits(w) }.
// ---------------------------------------------------------------------------
__global__ __launch_bounds__(256) void k_bucket(
    const int* __restrict__ ei, const float* __restrict__ ew,
    int* __restrict__ gcursor, int2* __restrict__ e_sw)
{
    __shared__ int h[NB];
    __shared__ int base[NB];
    __shared__ int off[NB];
    int tid = threadIdx.x;
    int e0 = blockIdx.x * CHUNK;
    int e1 = e0 + CHUNK; if (e1 > NE) e1 = NE;
    for (int b = tid; b < NB; b += 256) { h[b] = 0; off[b] = 0; }
    __syncthreads();
    for (int e = e0 + tid; e < e1; e += 256)
        atomicAdd(&h[ei[NE + e] >> BSHIFT], 1);
    __syncthreads();
    for (int b = tid; b < NB; b += 256)
        base[b] = atomicAdd(&gcursor[b], h[b]);
    __syncthreads();
    for (int e = e0 + tid; e < e1; e += 256) {
        int d = ei[NE + e];
        int b = d >> BSHIFT;
        int p = base[b] + atomicAdd(&off[b], 1);
        int2 v;
        v.x = ((d & (BSPAN - 1)) << 17) | ei[e];
        v.y = __float_as_int(ew[e]);
        e_sw[(size_t)b * CAP + p] = v;
    }
}

// ---------------------------------------------------------------------------
// Pass B: within-bucket counting sort by dl, IN PLACE via LDS stash.
// Emits rowptr2[d] = {beg, end} (absolute indices into e_sw).
// ---------------------------------------------------------------------------
__global__ __launch_bounds__(256) void k_sort(
    const int* __restrict__ gcursor, int2* __restrict__ e_sw,
    int2* __restrict__ rowptr2)
{
    __shared__ int2 stash[CAP];
    __shared__ int hist[BSPAN];
    __shared__ int startp[BSPAN];
    __shared__ int off[BSPAN];
    int b = blockIdx.x, tid = threadIdx.x;
    int cnt = gcursor[b];
    int2* es = e_sw + (size_t)b * CAP;
    for (int i = tid; i < BSPAN; i += 256) { hist[i] = 0; off[i] = 0; }
    __syncthreads();
    for (int i = tid; i < cnt; i += 256) {
        int2 v = es[i];
        stash[i] = v;
        atomicAdd(&hist[v.x >> 17], 1);
    }
    __syncthreads();
    if (tid < BSPAN) startp[tid] = hist[tid];
    __syncthreads();
    for (int o = 1; o < BSPAN; o <<= 1) {
        int v = (tid < BSPAN && tid >= o) ? startp[tid - o] : 0;
        __syncthreads();
        if (tid < BSPAN) startp[tid] += v;   // inclusive scan
        __syncthreads();
    }
    // exclusive start of dl = startp[dl] - hist[dl]
    for (int i = tid; i < cnt; i += 256) {
        int2 v = stash[i];
        int dl = v.x >> 17;
        int p = (startp[dl] - hist[dl]) + atomicAdd(&off[dl], 1);
        es[p] = v;
    }
    int d0 = b << BSHIFT;
    if (tid < BSPAN) {
        int d = d0 + tid;
        if (d < NN) {
            int beg = b * CAP + startp[tid] - hist[tid];
            int2 rp; rp.x = beg; rp.y = beg + hist[tid];
            rowptr2[d] = rp;
        }
    }
}

// ---------------------------------------------------------------------------
// y1 = x @ W1_rel.T   (N x 64 -> N x 32); one thread per node.
// ---------------------------------------------------------------------------
__global__ __launch_bounds__(256) void k_transform1(
    const float* __restrict__ x, const float* __restrict__ W1_rel,
    float* __restrict__ y1)
{
    int n = blockIdx.x * 256 + threadIdx.x;
    if (n >= NN) return;
    float xr[64];
    const float4* xrow = reinterpret_cast<const float4*>(x + (size_t)n * 64);
#pragma unroll
    for (int i = 0; i < 16; ++i) {
        float4 v = xrow[i];
        xr[4*i+0] = v.x; xr[4*i+1] = v.y; xr[4*i+2] = v.z; xr[4*i+3] = v.w;
    }
    float4* out = reinterpret_cast<float4*>(y1 + (size_t)n * 32);
#pragma unroll
    for (int og = 0; og < 8; ++og) {
        float a[4];
#pragma unroll
        for (int j = 0; j < 4; ++j) {
            const float* wrow = W1_rel + (og * 4 + j) * 64;
            float s = 0.f;
#pragma unroll
            for (int k = 0; k < 64; ++k) s += xr[k] * wrow[k];
            a[j] = s;
        }
        float4 v; v.x = a[0]; v.y = a[1]; v.z = a[2]; v.w = a[3];
        out[og] = v;
    }
}

// ---------------------------------------------------------------------------
// Reduce pass 1: 8 lanes per dst row; register accumulation; 4-edge unroll
// with zero-weight tail masking. No LDS, no atomics.
// ---------------------------------------------------------------------------
__global__ __launch_bounds__(256) void k_reduce1(
    const int2* __restrict__ rowptr2, const int2* __restrict__ e_sw,
    const float* __restrict__ y1, float* __restrict__ agg1)
{
    int idx = blockIdx.x * 256 + threadIdx.x;
    int d = idx >> 3;
    if (d >= NN) return;
    int g = idx & 7;
    int2 rp = rowptr2[d];
    int beg = rp.x, end = rp.y;
    float a0 = 0.f, a1 = 0.f, a2 = 0.f, a3 = 0.f;
    for (int e = beg; e < end; e += 4) {
        int eB = e + 1, eC = e + 2, eD = e + 3;
        int lim = end - 1;
        int2 pA = e_sw[e];
        int2 pB = e_sw[eB < lim ? eB : lim];
        int2 pC = e_sw[eC < lim ? eC : lim];
        int2 pD = e_sw[eD < lim ? eD : lim];
        float wA = __int_as_float(pA.y);
        float wB = eB < end ? __int_as_float(pB.y) : 0.f;
        float wC = eC < end ? __int_as_float(pC.y) : 0.f;
        float wD = eD < end ? __int_as_float(pD.y) : 0.f;
        float4 vA = *reinterpret_cast<const float4*>(y1 + (size_t)(pA.x & 0x1FFFF) * 32 + g * 4);
        float4 vB = *reinterpret_cast<const float4*>(y1 + (size_t)(pB.x & 0x1FFFF) * 32 + g * 4);
        float4 vC = *reinterpret_cast<const float4*>(y1 + (size_t)(pC.x & 0x1FFFF) * 32 + g * 4);
        float4 vD = *reinterpret_cast<const float4*>(y1 + (size_t)(pD.x & 0x1FFFF) * 32 + g * 4);
        a0 += vA.x * wA + vB.x * wB + vC.x * wC + vD.x * wD;
        a1 += vA.y * wA + vB.y * wB + vC.y * wC + vD.y * wD;
        a2 += vA.z * wA + vB.z * wB + vC.z * wC + vD.z * wD;
        a3 += vA.w * wA + vB.w * wB + vC.w * wC + vD.w * wD;
    }
    float4 o; o.x = a0; o.y = a1; o.z = a2; o.w = a3;
    *reinterpret_cast<float4*>(agg1 + (size_t)d * 32 + g * 4) = o;
}

// ---------------------------------------------------------------------------
// h = relu(agg1 + b1 + x @ W1_root.T); y2 = h @ W2_rel.T; r2 = h @ W2_root.T
// ---------------------------------------------------------------------------
__global__ __launch_bounds__(256) void k_node1(
    const float* __restrict__ x, const float* __restrict__ agg1,
    const float* __restrict__ W1_root, const float* __restrict__ b1,
    const float* __restrict__ W2_rel, const float* __restrict__ W2_root,
    float* __restrict__ y2, float* __restrict__ r2)
{
    int n = blockIdx.x * 256 + threadIdx.x;
    if (n >= NN) return;
    float xr[64];
    const float4* xrow = reinterpret_cast<const float4*>(x + (size_t)n * 64);
#pragma unroll
    for (int i = 0; i < 16; ++i) {
        float4 v = xrow[i];
        xr[4*i+0] = v.x; xr[4*i+1] = v.y; xr[4*i+2] = v.z; xr[4*i+3] = v.w;
    }
    float h[32];
    const float4* arow = reinterpret_cast<const float4*>(agg1 + (size_t)n * 32);
#pragma unroll
    for (int og = 0; og < 8; ++og) {
        float4 v = arow[og];
        h[og*4+0] = v.x; h[og*4+1] = v.y; h[og*4+2] = v.z; h[og*4+3] = v.w;
    }
#pragma unroll
    for (int o = 0; o < 32; ++o) {
        const float* wrow = W1_root + o * 64;
        float ssum = 0.f;
#pragma unroll
        for (int k = 0; k < 64; ++k) ssum += xr[k] * wrow[k];
        float t = h[o] + b1[o] + ssum;
        h[o] = t > 0.f ? t : 0.f;
    }
    float o2[8], o3[8];
#pragma unroll
    for (int j = 0; j < 8; ++j) {
        const float* wr = W2_rel  + j * 32;
        const float* wo = W2_root + j * 32;
        float s0 = 0.f, s1 = 0.f;
#pragma unroll
        for (int c = 0; c < 32; ++c) { s0 += h[c] * wr[c]; s1 += h[c] * wo[c]; }
        o2[j] = s0; o3[j] = s1;
    }
    float4* y2o = reinterpret_cast<float4*>(y2 + (size_t)n * 8);
    float4* r2o = reinterpret_cast<float4*>(r2 + (size_t)n * 8);
    float4 v0, v1;
    v0.x=o2[0]; v0.y=o2[1]; v0.z=o2[2]; v0.w=o2[3]; y2o[0]=v0;
    v1.x=o2[4]; v1.y=o2[5]; v1.z=o2[6]; v1.w=o2[7]; y2o[1]=v1;
    v0.x=o3[0]; v0.y=o3[1]; v0.z=o3[2]; v0.w=o3[3]; r2o[0]=v0;
    v1.x=o3[4]; v1.y=o3[5]; v1.z=o3[6]; v1.w=o3[7]; r2o[1]=v1;
}

// ---------------------------------------------------------------------------
// Reduce pass 2: 2 lanes per dst row (8 features); register accumulation;
// 4-edge unroll with zero-weight tail masking.
// ---------------------------------------------------------------------------
__global__ __launch_bounds__(256) void k_reduce2(
    const int2* __restrict__ rowptr2, const int2* __restrict__ e_sw,
    const float* __restrict__ y2, float* __restrict__ agg2)
{
    int idx = blockIdx.x * 256 + threadIdx.x;
    int d = idx >> 1;
    if (d >= NN) return;
    int g = idx & 1;
    int2 rp = rowptr2[d];
    int beg = rp.x, end = rp.y;
    float a0 = 0.f, a1 = 0.f, a2 = 0.f, a3 = 0.f;
    for (int e = beg; e < end; e += 4) {
        int eB = e + 1, eC = e + 2, eD = e + 3;
        int lim = end - 1;
        int2 pA = e_sw[e];
        int2 pB = e_sw[eB < lim ? eB : lim];
        int2 pC = e_sw[eC < lim ? eC : lim];
        int2 pD = e_sw[eD < lim ? eD : lim];
        float wA = __int_as_float(pA.y);
        float wB = eB < end ? __int_as_float(pB.y) : 0.f;
        float wC = eC < end ? __int_as_float(pC.y) : 0.f;
        float wD = eD < end ? __int_as_float(pD.y) : 0.f;
        float4 vA = *reinterpret_cast<const float4*>(y2 + (size_t)(pA.x & 0x1FFFF) * 8 + g * 4);
        float4 vB = *reinterpret_cast<const float4*>(y2 + (size_t)(pB.x & 0x1FFFF) * 8 + g * 4);
        float4 vC = *reinterpret_cast<const float4*>(y2 + (size_t)(pC.x & 0x1FFFF) * 8 + g * 4);
        float4 vD = *reinterpret_cast<const float4*>(y2 + (size_t)(pD.x & 0x1FFFF) * 8 + g * 4);
        a0 += vA.x * wA + vB.x * wB + vC.x * wC + vD.x * wD;
        a1 += vA.y * wA + vB.y * wB + vC.y * wC + vD.y * wD;
        a2 += vA.z * wA + vB.z * wB + vC.z * wC + vD.z * wD;
        a3 += vA.w * wA + vB.w * wB + vC.w * wC + vD.w * wD;
    }
    float4 o; o.x = a0; o.y = a1; o.z = a2; o.w = a3;
    *reinterpret_cast<float4*>(agg2 + (size_t)d * 8 + g * 4) = o;
}

// ---------------------------------------------------------------------------
// Final: h2 = agg2 + b2 + r2; emb = log_softmax(h2); out = relu([emb,x1]@W_lin.T+b)
// ---------------------------------------------------------------------------
__global__ __launch_bounds__(256) void k_final(
    const float* __restrict__ agg2, const float* __restrict__ r2,
    const float* __restrict__ x1, const float* __restrict__ b2,
    const float* __restrict__ W_lin, const float* __restrict__ b_lin,
    float* __restrict__ outv, float* __restrict__ emb)
{
    int n = blockIdx.x * 256 + threadIdx.x;
    if (n >= NN) return;
    const float4* arow = reinterpret_cast<const float4*>(agg2 + (size_t)n * 8);
    const float4* rrow = reinterpret_cast<const float4*>(r2   + (size_t)n * 8);
    float h2[8];
    {
        float4 a0 = arow[0], a1 = arow[1], r0 = rrow[0], r1 = rrow[1];
        h2[0]=a0.x+r0.x+b2[0]; h2[1]=a0.y+r0.y+b2[1];
        h2[2]=a0.z+r0.z+b2[2]; h2[3]=a0.w+r0.w+b2[3];
        h2[4]=a1.x+r1.x+b2[4]; h2[5]=a1.y+r1.y+b2[5];
        h2[6]=a1.z+r1.z+b2[6]; h2[7]=a1.w+r1.w+b2[7];
    }
    float m = h2[0];
#pragma unroll
    for (int j = 1; j < 8; ++j) m = fmaxf(m, h2[j]);
    float sum = 0.f;
#pragma unroll
    for (int j = 0; j < 8; ++j) sum += __expf(h2[j] - m);
    float lse = __logf(sum);
    float eb[8];
#pragma unroll
    for (int j = 0; j < 8; ++j) eb[j] = h2[j] - m - lse;
    float4* eo = reinterpret_cast<float4*>(emb + (size_t)n * 8);
    float4 v0, v1;
    v0.x=eb[0]; v0.y=eb[1]; v0.z=eb[2]; v0.w=eb[3]; eo[0]=v0;
    v1.x=eb[4]; v1.y=eb[5]; v1.z=eb[6]; v1.w=eb[7]; eo[1]=v1;
    float acc = b_lin[0] + x1[n] * W_lin[8];
#pragma unroll
    for (int j = 0; j < 8; ++j) acc += eb[j] * W_lin[j];
    outv[n] = acc > 0.f ? acc : 0.f;
}

// ---------------------------------------------------------------------------
extern "C" void kernel_launch(void* const* d_in, const int* in_sizes, int n_in,
                              void* d_out, int out_size, void* d_ws, size_t ws_size,
                              hipStream_t stream) {
    const float* x      = (const float*)d_in[0];
    const int*   ei     = (const int*)  d_in[1];
    const float* ew     = (const float*)d_in[2];
    const float* x1     = (const float*)d_in[3];
    const float* W1_rel = (const float*)d_in[4];
    const float* b1     = (const float*)d_in[5];
    const float* W1_root= (const float*)d_in[6];
    const float* W2_rel = (const float*)d_in[7];
    const float* b2     = (const float*)d_in[8];
    const float* W2_root= (const float*)d_in[9];
    const float* W_lin  = (const float*)d_in[10];
    const float* b_lin  = (const float*)d_in[11];

    float* ws    = (float*)d_ws;
    float* y1    = ws;                           // N*32
    float* agg1  = y1   + (size_t)NN * 32;       // N*32
    float* y2    = agg1 + (size_t)NN * 32;       // N*8
    float* r2    = y2   + (size_t)NN * 8;        // N*8
    float* agg2  = r2   + (size_t)NN * 8;        // N*8
    int*   gcursor = (int*)(agg2 + (size_t)NN * 8);     // NB (+pad to even)
    int2*  rowptr2 = (int2*)(gcursor + NB + (NB & 1));  // NN int2
    int2*  e_sw    = rowptr2 + NN;                      // NB*CAP int2

    float* outv = (float*)d_out;             // N   (output 0)
    float* emb  = outv + NN;                 // N*8 (output 1)

    hipMemsetAsync(gcursor, 0, NB * sizeof(int), stream);

    int nbN = (NN + 255) / 256;
    k_bucket<<<NBLK, 256, 0, stream>>>(ei, ew, gcursor, e_sw);
    k_sort<<<NB, 256, 0, stream>>>(gcursor, e_sw, rowptr2);
    k_transform1<<<nbN, 256, 0, stream>>>(x, W1_rel, y1);
    k_reduce1<<<(NN * 8 + 255) / 256, 256, 0, stream>>>(rowptr2, e_sw, y1, agg1);
    k_node1<<<nbN, 256, 0, stream>>>(x, agg1, W1_root, b1, W2_rel, W2_root, y2, r2);
    k_reduce2<<<(NN * 2 + 255) / 256, 256, 0, stream>>>(rowptr2, e_sw, y2, agg2);
    k_final<<<nbN, 256, 0, stream>>>(agg2, r2, x1, b2, W_lin, b_lin, outv, emb);
}

// Round 6
// 251.441 us; speedup vs baseline: 3.8985x; 1.0396x over previous
//
#include <hip/hip_runtime.h>
#include <hip/hip_bf16.h>

constexpr int NN = 100000;   // nodes
constexpr int NE = 3200000;  // edges
constexpr int BSHIFT = 8;                       // 256 dsts per bucket
constexpr int BSPAN  = 1 << BSHIFT;
constexpr int NB = (NN + BSPAN - 1) >> BSHIFT;  // 391 buckets
constexpr int CAP = 9216;                       // mean 8192 + 11 sigma; mult of 8
constexpr int NBLK = 512;                       // bucket-pass blocks
constexpr int CHUNK = (NE + NBLK - 1) / NBLK;   // 6250 edges per block
constexpr int SLOTS = CAP / 1024;               // 9 register-held edges/thread in k_sort

// ---------------------------------------------------------------------------
// Pass A: coarse bucket sort by dst>>8.
// Payload: int2 { (dst&255)<<17 | src , bits(w) }.  (src<2^17, dl<2^8)
// 128B per-(block,bucket) segments keep scattered-write line amplification low.
// ---------------------------------------------------------------------------
__global__ __launch_bounds__(256) void k_bucket(
    const int* __restrict__ ei, const float* __restrict__ ew,
    int* __restrict__ gcursor, int2* __restrict__ e_sw)
{
    __shared__ int h[NB];
    __shared__ int base[NB];
    int tid = threadIdx.x;
    int e0 = blockIdx.x * CHUNK;
    int e1 = e0 + CHUNK; if (e1 > NE) e1 = NE;
    for (int b = tid; b < NB; b += 256) h[b] = 0;
    __syncthreads();
    for (int e = e0 + tid; e < e1; e += 256)
        atomicAdd(&h[ei[NE + e] >> BSHIFT], 1);
    __syncthreads();
    for (int b = tid; b < NB; b += 256) {
        int c = h[b];
        base[b] = c ? atomicAdd(&gcursor[b], c) : 0;
    }
    __syncthreads();
    for (int e = e0 + tid; e < e1; e += 256) {
        int d = ei[NE + e];
        int b = d >> BSHIFT;
        int p = atomicAdd(&base[b], 1);
        int2 v;
        v.x = ((d & (BSPAN - 1)) << 17) | ei[e];
        v.y = __float_as_int(ew[e]);
        e_sw[(size_t)b * CAP + p] = v;
    }
}

// ---------------------------------------------------------------------------
// Pass B: within-bucket counting sort by dl, IN PLACE, edges held in
// registers (statically indexed -> VGPRs, no scratch). LDS = 3KB counters.
// Emits rowptr2[d] = {beg, end} (absolute indices into e_sw).
// ---------------------------------------------------------------------------
__global__ __launch_bounds__(1024) void k_sort(
    const int* __restrict__ gcursor, int2* __restrict__ e_sw,
    int2* __restrict__ rowptr2)
{
    __shared__ int hist[BSPAN];
    __shared__ int startp[BSPAN];
    __shared__ int off[BSPAN];
    int b = blockIdx.x, tid = threadIdx.x;
    int cnt = gcursor[b];
    int2* es = e_sw + (size_t)b * CAP;
    if (tid < BSPAN) hist[tid] = 0;
    __syncthreads();
    int2 held[SLOTS];
#pragma unroll
    for (int k = 0; k < SLOTS; ++k) {
        int i = tid + k * 1024;
        if (i < cnt) {
            int2 v = es[i];
            held[k] = v;
            atomicAdd(&hist[v.x >> 17], 1);
        }
    }
    __syncthreads();
    if (tid < BSPAN) startp[tid] = hist[tid];
    __syncthreads();
    for (int o = 1; o < BSPAN; o <<= 1) {
        int v = (tid < BSPAN && tid >= o) ? startp[tid - o] : 0;
        __syncthreads();
        if (tid < BSPAN) startp[tid] += v;   // inclusive scan
        __syncthreads();
    }
    // exclusive start of dl = startp[dl] - hist[dl]
    int d0 = b << BSHIFT;
    if (tid < BSPAN) {
        int beg_rel = startp[tid] - hist[tid];
        off[tid] = beg_rel;
        int d = d0 + tid;
        if (d < NN) {
            int beg = b * CAP + beg_rel;
            int2 rp; rp.x = beg; rp.y = beg + hist[tid];
            rowptr2[d] = rp;
        }
    }
    __syncthreads();
#pragma unroll
    for (int k = 0; k < SLOTS; ++k) {
        int i = tid + k * 1024;
        if (i < cnt) {
            int2 v = held[k];
            int p = atomicAdd(&off[v.x >> 17], 1);
            es[p] = v;
        }
    }
}

// ---------------------------------------------------------------------------
// y1 = x @ W1_rel.T   (N x 64 -> N x 32); one thread per node.
// ---------------------------------------------------------------------------
__global__ __launch_bounds__(256) void k_transform1(
    const float* __restrict__ x, const float* __restrict__ W1_rel,
    float* __restrict__ y1)
{
    int n = blockIdx.x * 256 + threadIdx.x;
    if (n >= NN) return;
    float xr[64];
    const float4* xrow = reinterpret_cast<const float4*>(x + (size_t)n * 64);
#pragma unroll
    for (int i = 0; i < 16; ++i) {
        float4 v = xrow[i];
        xr[4*i+0] = v.x; xr[4*i+1] = v.y; xr[4*i+2] = v.z; xr[4*i+3] = v.w;
    }
    float4* out = reinterpret_cast<float4*>(y1 + (size_t)n * 32);
#pragma unroll
    for (int og = 0; og < 8; ++og) {
        float a[4];
#pragma unroll
        for (int j = 0; j < 4; ++j) {
            const float* wrow = W1_rel + (og * 4 + j) * 64;
            float s = 0.f;
#pragma unroll
            for (int k = 0; k < 64; ++k) s += xr[k] * wrow[k];
            a[j] = s;
        }
        float4 v; v.x = a[0]; v.y = a[1]; v.z = a[2]; v.w = a[3];
        out[og] = v;
    }
}

// ---------------------------------------------------------------------------
// Reduce pass 1: 8 lanes per dst row; register accumulation; 4-edge unroll
// with zero-weight tail masking. No LDS, no atomics.
// ---------------------------------------------------------------------------
__global__ __launch_bounds__(256) void k_reduce1(
    const int2* __restrict__ rowptr2, const int2* __restrict__ e_sw,
    const float* __restrict__ y1, float* __restrict__ agg1)
{
    int idx = blockIdx.x * 256 + threadIdx.x;
    int d = idx >> 3;
    if (d >= NN) return;
    int g = idx & 7;
    int2 rp = rowptr2[d];
    int beg = rp.x, end = rp.y;
    float a0 = 0.f, a1 = 0.f, a2 = 0.f, a3 = 0.f;
    for (int e = beg; e < end; e += 4) {
        int eB = e + 1, eC = e + 2, eD = e + 3;
        int lim = end - 1;
        int2 pA = e_sw[e];
        int2 pB = e_sw[eB < lim ? eB : lim];
        int2 pC = e_sw[eC < lim ? eC : lim];
        int2 pD = e_sw[eD < lim ? eD : lim];
        float wA = __int_as_float(pA.y);
        float wB = eB < end ? __int_as_float(pB.y) : 0.f;
        float wC = eC < end ? __int_as_float(pC.y) : 0.f;
        float wD = eD < end ? __int_as_float(pD.y) : 0.f;
        float4 vA = *reinterpret_cast<const float4*>(y1 + (size_t)(pA.x & 0x1FFFF) * 32 + g * 4);
        float4 vB = *reinterpret_cast<const float4*>(y1 + (size_t)(pB.x & 0x1FFFF) * 32 + g * 4);
        float4 vC = *reinterpret_cast<const float4*>(y1 + (size_t)(pC.x & 0x1FFFF) * 32 + g * 4);
        float4 vD = *reinterpret_cast<const float4*>(y1 + (size_t)(pD.x & 0x1FFFF) * 32 + g * 4);
        a0 += vA.x * wA + vB.x * wB + vC.x * wC + vD.x * wD;
        a1 += vA.y * wA + vB.y * wB + vC.y * wC + vD.y * wD;
        a2 += vA.z * wA + vB.z * wB + vC.z * wC + vD.z * wD;
        a3 += vA.w * wA + vB.w * wB + vC.w * wC + vD.w * wD;
    }
    float4 o; o.x = a0; o.y = a1; o.z = a2; o.w = a3;
    *reinterpret_cast<float4*>(agg1 + (size_t)d * 32 + g * 4) = o;
}

// ---------------------------------------------------------------------------
// h = relu(agg1 + b1 + x @ W1_root.T); y2 = h @ W2_rel.T; r2 = h @ W2_root.T
// ---------------------------------------------------------------------------
__global__ __launch_bounds__(256) void k_node1(
    const float* __restrict__ x, const float* __restrict__ agg1,
    const float* __restrict__ W1_root, const float* __restrict__ b1,
    const float* __restrict__ W2_rel, const float* __restrict__ W2_root,
    float* __restrict__ y2, float* __restrict__ r2)
{
    int n = blockIdx.x * 256 + threadIdx.x;
    if (n >= NN) return;
    float xr[64];
    const float4* xrow = reinterpret_cast<const float4*>(x + (size_t)n * 64);
#pragma unroll
    for (int i = 0; i < 16; ++i) {
        float4 v = xrow[i];
        xr[4*i+0] = v.x; xr[4*i+1] = v.y; xr[4*i+2] = v.z; xr[4*i+3] = v.w;
    }
    float h[32];
    const float4* arow = reinterpret_cast<const float4*>(agg1 + (size_t)n * 32);
#pragma unroll
    for (int og = 0; og < 8; ++og) {
        float4 v = arow[og];
        h[og*4+0] = v.x; h[og*4+1] = v.y; h[og*4+2] = v.z; h[og*4+3] = v.w;
    }
#pragma unroll
    for (int o = 0; o < 32; ++o) {
        const float* wrow = W1_root + o * 64;
        float ssum = 0.f;
#pragma unroll
        for (int k = 0; k < 64; ++k) ssum += xr[k] * wrow[k];
        float t = h[o] + b1[o] + ssum;
        h[o] = t > 0.f ? t : 0.f;
    }
    float o2[8], o3[8];
#pragma unroll
    for (int j = 0; j < 8; ++j) {
        const float* wr = W2_rel  + j * 32;
        const float* wo = W2_root + j * 32;
        float s0 = 0.f, s1 = 0.f;
#pragma unroll
        for (int c = 0; c < 32; ++c) { s0 += h[c] * wr[c]; s1 += h[c] * wo[c]; }
        o2[j] = s0; o3[j] = s1;
    }
    float4* y2o = reinterpret_cast<float4*>(y2 + (size_t)n * 8);
    float4* r2o = reinterpret_cast<float4*>(r2 + (size_t)n * 8);
    float4 v0, v1;
    v0.x=o2[0]; v0.y=o2[1]; v0.z=o2[2]; v0.w=o2[3]; y2o[0]=v0;
    v1.x=o2[4]; v1.y=o2[5]; v1.z=o2[6]; v1.w=o2[7]; y2o[1]=v1;
    v0.x=o3[0]; v0.y=o3[1]; v0.z=o3[2]; v0.w=o3[3]; r2o[0]=v0;
    v1.x=o3[4]; v1.y=o3[5]; v1.z=o3[6]; v1.w=o3[7]; r2o[1]=v1;
}

// ---------------------------------------------------------------------------
// Reduce pass 2: 2 lanes per dst row (8 features); register accumulation;
// 4-edge unroll with zero-weight tail masking.
// ---------------------------------------------------------------------------
__global__ __launch_bounds__(256) void k_reduce2(
    const int2* __restrict__ rowptr2, const int2* __restrict__ e_sw,
    const float* __restrict__ y2, float* __restrict__ agg2)
{
    int idx = blockIdx.x * 256 + threadIdx.x;
    int d = idx >> 1;
    if (d >= NN) return;
    int g = idx & 1;
    int2 rp = rowptr2[d];
    int beg = rp.x, end = rp.y;
    float a0 = 0.f, a1 = 0.f, a2 = 0.f, a3 = 0.f;
    for (int e = beg; e < end; e += 4) {
        int eB = e + 1, eC = e + 2, eD = e + 3;
        int lim = end - 1;
        int2 pA = e_sw[e];
        int2 pB = e_sw[eB < lim ? eB : lim];
        int2 pC = e_sw[eC < lim ? eC : lim];
        int2 pD = e_sw[eD < lim ? eD : lim];
        float wA = __int_as_float(pA.y);
        float wB = eB < end ? __int_as_float(pB.y) : 0.f;
        float wC = eC < end ? __int_as_float(pC.y) : 0.f;
        float wD = eD < end ? __int_as_float(pD.y) : 0.f;
        float4 vA = *reinterpret_cast<const float4*>(y2 + (size_t)(pA.x & 0x1FFFF) * 8 + g * 4);
        float4 vB = *reinterpret_cast<const float4*>(y2 + (size_t)(pB.x & 0x1FFFF) * 8 + g * 4);
        float4 vC = *reinterpret_cast<const float4*>(y2 + (size_t)(pC.x & 0x1FFFF) * 8 + g * 4);
        float4 vD = *reinterpret_cast<const float4*>(y2 + (size_t)(pD.x & 0x1FFFF) * 8 + g * 4);
        a0 += vA.x * wA + vB.x * wB + vC.x * wC + vD.x * wD;
        a1 += vA.y * wA + vB.y * wB + vC.y * wC + vD.y * wD;
        a2 += vA.z * wA + vB.z * wB + vC.z * wC + vD.z * wD;
        a3 += vA.w * wA + vB.w * wB + vC.w * wC + vD.w * wD;
    }
    float4 o; o.x = a0; o.y = a1; o.z = a2; o.w = a3;
    *reinterpret_cast<float4*>(agg2 + (size_t)d * 8 + g * 4) = o;
}

// ---------------------------------------------------------------------------
// Final: h2 = agg2 + b2 + r2; emb = log_softmax(h2); out = relu([emb,x1]@W_lin.T+b)
// ---------------------------------------------------------------------------
__global__ __launch_bounds__(256) void k_final(
    const float* __restrict__ agg2, const float* __restrict__ r2,
    const float* __restrict__ x1, const float* __restrict__ b2,
    const float* __restrict__ W_lin, const float* __restrict__ b_lin,
    float* __restrict__ outv, float* __restrict__ emb)
{
    int n = blockIdx.x * 256 + threadIdx.x;
    if (n >= NN) return;
    const float4* arow = reinterpret_cast<const float4*>(agg2 + (size_t)n * 8);
    const float4* rrow = reinterpret_cast<const float4*>(r2   + (size_t)n * 8);
    float h2[8];
    {
        float4 a0 = arow[0], a1 = arow[1], r0 = rrow[0], r1 = rrow[1];
        h2[0]=a0.x+r0.x+b2[0]; h2[1]=a0.y+r0.y+b2[1];
        h2[2]=a0.z+r0.z+b2[2]; h2[3]=a0.w+r0.w+b2[3];
        h2[4]=a1.x+r1.x+b2[4]; h2[5]=a1.y+r1.y+b2[5];
        h2[6]=a1.z+r1.z+b2[6]; h2[7]=a1.w+r1.w+b2[7];
    }
    float m = h2[0];
#pragma unroll
    for (int j = 1; j < 8; ++j) m = fmaxf(m, h2[j]);
    float sum = 0.f;
#pragma unroll
    for (int j = 0; j < 8; ++j) sum += __expf(h2[j] - m);
    float lse = __logf(sum);
    float eb[8];
#pragma unroll
    for (int j = 0; j < 8; ++j) eb[j] = h2[j] - m - lse;
    float4* eo = reinterpret_cast<float4*>(emb + (size_t)n * 8);
    float4 v0, v1;
    v0.x=eb[0]; v0.y=eb[1]; v0.z=eb[2]; v0.w=eb[3]; eo[0]=v0;
    v1.x=eb[4]; v1.y=eb[5]; v1.z=eb[6]; v1.w=eb[7]; eo[1]=v1;
    float acc = b_lin[0] + x1[n] * W_lin[8];
#pragma unroll
    for (int j = 0; j < 8; ++j) acc += eb[j] * W_lin[j];
    outv[n] = acc > 0.f ? acc : 0.f;
}

// ---------------------------------------------------------------------------
extern "C" void kernel_launch(void* const* d_in, const int* in_sizes, int n_in,
                              void* d_out, int out_size, void* d_ws, size_t ws_size,
                              hipStream_t stream) {
    const float* x      = (const float*)d_in[0];
    const int*   ei     = (const int*)  d_in[1];
    const float* ew     = (const float*)d_in[2];
    const float* x1     = (const float*)d_in[3];
    const float* W1_rel = (const float*)d_in[4];
    const float* b1     = (const float*)d_in[5];
    const float* W1_root= (const float*)d_in[6];
    const float* W2_rel = (const float*)d_in[7];
    const float* b2     = (const float*)d_in[8];
    const float* W2_root= (const float*)d_in[9];
    const float* W_lin  = (const float*)d_in[10];
    const float* b_lin  = (const float*)d_in[11];

    float* ws    = (float*)d_ws;
    float* y1    = ws;                           // N*32
    float* agg1  = y1   + (size_t)NN * 32;       // N*32
    float* y2    = agg1 + (size_t)NN * 32;       // N*8
    float* r2    = y2   + (size_t)NN * 8;        // N*8
    float* agg2  = r2   + (size_t)NN * 8;        // N*8
    int*   gcursor = (int*)(agg2 + (size_t)NN * 8);     // NB, padded to 1024
    int2*  rowptr2 = (int2*)(gcursor + 1024);           // NN int2
    int2*  e_sw    = rowptr2 + NN;                      // NB*CAP int2 (64B-aligned)

    float* outv = (float*)d_out;             // N   (output 0)
    float* emb  = outv + NN;                 // N*8 (output 1)

    hipMemsetAsync(gcursor, 0, NB * sizeof(int), stream);

    int nbN = (NN + 255) / 256;
    k_bucket<<<NBLK, 256, 0, stream>>>(ei, ew, gcursor, e_sw);
    k_sort<<<NB, 1024, 0, stream>>>(gcursor, e_sw, rowptr2);
    k_transform1<<<nbN, 256, 0, stream>>>(x, W1_rel, y1);
    k_reduce1<<<(NN * 8 + 255) / 256, 256, 0, stream>>>(rowptr2, e_sw, y1, agg1);
    k_node1<<<nbN, 256, 0, stream>>>(x, agg1, W1_root, b1, W2_rel, W2_root, y2, r2);
    k_reduce2<<<(NN * 2 + 255) / 256, 256, 0, stream>>>(rowptr2, e_sw, y2, agg2);
    k_final<<<nbN, 256, 0, stream>>>(agg2, r2, x1, b2, W_lin, b_lin, outv, emb);
}